// Round 16
// baseline (11217.290 us; speedup 1.0000x reference)
//
#include <hip/hip_runtime.h>
#include <math.h>

#define BB   256
#define HH   512
#define TT   64
#define NOUT 33
#define CD   128
#define NTHR 1024
#define NWG  512
#define LOFF (4*HH*HH)
#define SZ   (HH*BB)            // 131072 floats
#define FC2OFF 4194304          // 128 i-slices * 32768 floats

typedef float f16v __attribute__((ext_vector_type(16)));
typedef const __attribute__((address_space(4))) float cfloat;
typedef const __attribute__((address_space(4))) f16v  cf16v;

__device__ __forceinline__ float sigm(float x)  { return 1.0f/(1.0f+expf(-x)); }
__device__ __forceinline__ float lrelu(float x) { return x >= 0.0f ? x : 0.01f*x; }

// memory-side coherent access (cross-XCD safe without fences; proven R11-R15)
__device__ __forceinline__ float gld(const float* p) {
  return __hip_atomic_load(p, __ATOMIC_RELAXED, __HIP_MEMORY_SCOPE_AGENT);
}
__device__ __forceinline__ void gst(float* p, float v) {
  __hip_atomic_store(p, v, __ATOMIC_RELAXED, __HIP_MEMORY_SCOPE_AGENT);
}
__device__ __forceinline__ unsigned gldu(const unsigned* p) {
  return __hip_atomic_load(p, __ATOMIC_RELAXED, __HIP_MEMORY_SCOPE_AGENT);
}

// provably-uniform constant-AS pointer -> s_load scalar stream (proven R10+)
__device__ __forceinline__ cfloat* cptr(const float* p) {
  unsigned long long u = (unsigned long long)p;
  unsigned lo = __builtin_amdgcn_readfirstlane((unsigned)u);
  unsigned hi = __builtin_amdgcn_readfirstlane((unsigned)(u >> 32));
  return (cfloat*)((((unsigned long long)hi) << 32) | (unsigned long long)lo);
}

// Per-j-group barrier: 128 WGs = 4 subgroups of 32 -> group counter(4) -> gen.
// Monotonic counters; fence only at the init barrier.
__device__ __forceinline__ void gbar(unsigned* bar, unsigned ep, int j, int sg, bool fence) {
  __syncthreads();
  if (threadIdx.x == 0) {
    if (fence) __builtin_amdgcn_fence(__ATOMIC_RELEASE, "agent");
    unsigned old = __hip_atomic_fetch_add(&bar[(j*4+sg)*16], 1u, __ATOMIC_RELAXED, __HIP_MEMORY_SCOPE_AGENT);
    if (old == ep*32u + 31u) {
      unsigned o2 = __hip_atomic_fetch_add(&bar[256 + j*16], 1u, __ATOMIC_RELAXED, __HIP_MEMORY_SCOPE_AGENT);
      if (o2 == ep*4u + 3u)
        __hip_atomic_store(&bar[320 + j*16], ep+1u, __ATOMIC_RELAXED, __HIP_MEMORY_SCOPE_AGENT);
    }
    while (gldu(&bar[320 + j*16]) < ep+1u) __builtin_amdgcn_s_sleep(1);
    if (fence) __builtin_amdgcn_fence(__ATOMIC_ACQUIRE, "agent");
  }
  __syncthreads();
}

// ---- weight transpose (identical layout to R15) ----
// LSTM per i: [l 2][k 512][32] ; 32 = [Wi r0..15 | Wh r0..15], r = u*4+g, hu = i*4+u
// fc2 per i:  [k 512][4 rows]
extern "C" __global__ void __launch_bounds__(256)
transpose_weights(const float* __restrict__ Wih, const float* __restrict__ Whh,
                  const float* __restrict__ fc2W, float* __restrict__ wsT)
{
  const int i = blockIdx.x, tid = threadIdx.x;
  float* dst = wsT + (size_t)i*32768;
  #pragma unroll 1
  for (int idx = tid; idx < 32768; idx += 256) {
    int slot = idx & 31, k = (idx>>5)&511, l = idx>>14;
    int a = slot>>4, r = slot&15, u = r>>2, g = r&3;
    int hu = i*4 + u;
    const float* src = a ? Whh : Wih;
    dst[idx] = src[(size_t)l*LOFF + (size_t)(g*HH+hu)*HH + k];
  }
  float* dstf = wsT + FC2OFF + (size_t)i*2048;
  #pragma unroll 1
  for (int idx = tid; idx < 2048; idx += 256) {
    int r = idx & 3, k = idx >> 2;
    dstf[idx] = fc2W[(size_t)(i*4+r)*HH + k];
  }
}

// LSTM layer phase. Wave ks (16): 32-k slice, 16 gate rows, 64 b (1/lane).
// 8-k ping-pong prefetch; weights via AS4 scalar stream.
__device__ __forceinline__ void lstm_phase(const float* __restrict__ wTl,
    const float* __restrict__ bias, float* __restrict__ red, float* __restrict__ gbuf,
    const float* __restrict__ xsrc, const float* __restrict__ hsrc,
    float* __restrict__ hdst, float& creg, int i, int j, int tid)
{
  const int lane = tid & 63, ks = tid >> 6;
  cf16v* wp = (cf16v*)cptr(wTl + (size_t)(ks*32)*32);
  const int bo = j*64 + lane;
  const float* xp = xsrc + (size_t)(ks*32)*BB + bo;
  const float* hp = hsrc + (size_t)(ks*32)*BB + bo;

  float acc[16];
  #pragma unroll
  for (int r = 0; r < 16; ++r) acc[r] = 0.f;

  float qA[16], qB[16];
  #pragma unroll
  for (int kk = 0; kk < 8; ++kk) {
    qA[kk*2]   = gld(xp + kk*BB);
    qA[kk*2+1] = gld(hp + kk*BB);
  }
  #pragma unroll
  for (int c = 0; c < 4; ++c) {
    float* q = (c & 1) ? qB : qA;
    float* p = (c & 1) ? qA : qB;
    if (c < 3) {
      #pragma unroll
      for (int kk = 0; kk < 8; ++kk) {
        p[kk*2]   = gld(xp + (c*8+8+kk)*BB);
        p[kk*2+1] = gld(hp + (c*8+8+kk)*BB);
      }
    }
    #pragma unroll
    for (int kk = 0; kk < 8; ++kk) {
      f16v wi = wp[(c*8+kk)*2];
      f16v wh = wp[(c*8+kk)*2+1];
      float xv = q[kk*2], hv = q[kk*2+1];
      #pragma unroll
      for (int r = 0; r < 16; ++r) acc[r] += wi[r]*xv + wh[r]*hv;
    }
  }
  #pragma unroll
  for (int r = 0; r < 16; ++r) red[(size_t)(ks*16 + r)*64 + lane] = acc[r];
  __syncthreads();
  // stage 1: parallel gate-row sums (1024 threads)
  {
    const int row = tid >> 6, b = tid & 63;
    float s = bias[row];
    #pragma unroll
    for (int q = 0; q < 16; ++q) s += red[(size_t)(q*16 + row)*64 + b];
    gbuf[row*64 + b] = s;
  }
  __syncthreads();
  // stage 2: pointwise (256 threads: 4 hu x 64 b)
  if (tid < 256) {
    const int lhu = tid >> 6, b = tid & 63;
    float i_g = sigm(gbuf[(lhu*4+0)*64 + b]);
    float f_g = sigm(gbuf[(lhu*4+1)*64 + b]);
    float g_g = tanhf(gbuf[(lhu*4+2)*64 + b]);
    float o_g = sigm(gbuf[(lhu*4+3)*64 + b]);
    float cn = f_g*creg + i_g*g_g;
    creg = cn;
    gst(hdst + (size_t)(i*4+lhu)*BB + j*64 + b, o_g*tanhf(cn));
  }
}

// fc2 phase: wave ks (16): 32-k slice, 4 rows, 64 b (1/lane).
__device__ __forceinline__ void fc2_phase(const float* __restrict__ h2src,
    const float* __restrict__ wsTf, float* __restrict__ yb,
    const float* lds_bc, const float* condY_l, float* __restrict__ red,
    int i, int j, int tid)
{
  const int lane = tid & 63, ks = tid >> 6;
  cf16v* wp = (cf16v*)cptr(wsTf + (size_t)(ks*32)*4);   // f16v = 4 k x 4 rows
  const int bo = j*64 + lane;
  const float* hp = h2src + (size_t)(ks*32)*BB + bo;
  float acc[4] = {0.f, 0.f, 0.f, 0.f};
  float qA[8], qB[8];
  #pragma unroll
  for (int kk = 0; kk < 8; ++kk) qA[kk] = gld(hp + kk*BB);
  #pragma unroll
  for (int c = 0; c < 4; ++c) {
    float* q = (c & 1) ? qB : qA;
    float* p = (c & 1) ? qA : qB;
    if (c < 3) {
      #pragma unroll
      for (int kk = 0; kk < 8; ++kk) p[kk] = gld(hp + (c*8+8+kk)*BB);
    }
    #pragma unroll
    for (int kk2 = 0; kk2 < 2; ++kk2) {
      f16v wv = wp[c*2 + kk2];
      #pragma unroll
      for (int k4 = 0; k4 < 4; ++k4) {
        float hv = q[kk2*4 + k4];
        #pragma unroll
        for (int r = 0; r < 4; ++r) acc[r] += wv[k4*4 + r]*hv;
      }
    }
  }
  #pragma unroll
  for (int r = 0; r < 4; ++r) red[(size_t)(ks*4 + r)*64 + lane] = acc[r];
  __syncthreads();
  if (tid < 256) {
    const int r = tid >> 6, b = tid & 63;
    float s = lds_bc[r] + condY_l[r*64 + b];
    #pragma unroll
    for (int q = 0; q < 16; ++q) s += red[(size_t)(q*4 + r)*64 + b];
    gst(yb + (size_t)(i*4+r)*BB + j*64 + b, lrelu(s));
  }
}

extern "C" __global__ void __launch_bounds__(NTHR)
decoder_kernel(const float* __restrict__ h0, const float* __restrict__ c0,
               const float* __restrict__ conds, const float* __restrict__ emb,
               const float* __restrict__ wsTW, const float* __restrict__ bih,
               const float* __restrict__ bhh, const float* __restrict__ fcW,
               const float* __restrict__ fcb, const float* __restrict__ fc2W,
               const float* __restrict__ fc2b, const float* __restrict__ fc3W,
               const float* __restrict__ fc3b,
               float* __restrict__ out, unsigned* bar, float* wsf)
{
  const int w = blockIdx.x;
  const int i = w & 127, j = w >> 7;    // 4 independent j-groups of 128 WGs
  const int sg = (i >> 5) & 3;
  const int tid = threadIdx.x;

  float* xbuf = wsf;
  float* h1a = wsf + 1*SZ;  float* h1b = wsf + 2*SZ;
  float* h2a = wsf + 3*SZ;  float* h2b = wsf + 4*SZ;
  float* yb  = wsf + 5*SZ;
  float* condb = wsf + 6*SZ;
  const float* wTi  = wsTW + (size_t)i*32768;
  const float* wsTf = wsTW + FC2OFF + (size_t)i*2048;

  __shared__ float red[16384];        // 64KB
  __shared__ float gbuf[1024];        // 4KB gate sums
  __shared__ float lds_y[HH];
  __shared__ float part[NOUT][17];
  __shared__ float condY_l[256];
  __shared__ float lds_b1[16], lds_b2[16], lds_bc[4];
  __shared__ int   lds_act;
  // total ~75KB -> 2 WG/CU, 8 waves/SIMD

  if (tid < 16) {
    int u = tid >> 2, g = tid & 3;
    int hu = i*4 + u;
    lds_b1[tid] = bih[g*HH+hu] + bhh[g*HH+hu];
    lds_b2[tid] = bih[4*HH + g*HH+hu] + bhh[4*HH + g*HH+hu];
  }
  if (tid < 4) lds_bc[tid] = fc2b[i*4 + tid];

  // ---- init (j-duplicated writes are identical -> benign) ----
  {
    int u = tid >> 8, b = tid & 255;
    int hug = i*4 + u;
    h1a[(size_t)hug*BB + b] = h0[(size_t)b*HH + hug];
    h2a[(size_t)hug*BB + b] = h0[(size_t)(BB+b)*HH + hug];
    xbuf[(size_t)hug*BB + b] = (hug < HH-1) ? emb[hug] : 0.0f;  // emb[SOS=0], dur=0
    const float* crow = conds + (size_t)b*CD;
    cfloat* fr = cptr(fcW + (size_t)hug*CD);
    float s = fcb[hug];
    #pragma unroll 4
    for (int q = 0; q < CD; q += 4)
      s += fr[q]*crow[q] + fr[q+1]*crow[q+1] + fr[q+2]*crow[q+2] + fr[q+3]*crow[q+3];
    condb[(size_t)hug*BB + b] = lrelu(s);
  }
  float c1 = 0.f, c2 = 0.f;
  if (tid < 256) {
    int lhu = tid >> 6, b = tid & 63;
    int hug = i*4 + lhu, bg = j*64 + b;
    c1 = c0[(size_t)bg*HH + hug];
    c2 = c0[(size_t)(BB+bg)*HH + hug];
  }
  unsigned ep = 0;
  gbar(bar, ep++, j, sg, true);

  // condY_l[r][b]: cond branch through fc2 (step-invariant, WG-private)
  if (tid < 256) {
    int r = tid >> 6, b = tid & 63, bg = j*64 + b;
    cfloat* wr = cptr(fc2W + (size_t)(i*4+r)*HH);
    float s = 0.f;
    #pragma unroll 4
    for (int k = 0; k < HH; ++k) s += wr[k]*condb[(size_t)k*BB + bg];
    condY_l[r*64 + b] = s;
  }
  __syncthreads();

  const bool dOwner = (i < 64);
  const int  drow   = j*64 + i;       // batch row owned in phase D

  for (int t = 0; t < TT; ++t) {
    float* h1r = (t&1) ? h1b : h1a;  float* h1w = (t&1) ? h1a : h1b;
    float* h2r = (t&1) ? h2b : h2a;  float* h2w = (t&1) ? h2a : h2b;

    lstm_phase(wTi,         lds_b1, red, gbuf, xbuf, h1r, h1w, c1, i, j, tid);
    gbar(bar, ep++, j, sg, false);
    lstm_phase(wTi + 16384, lds_b2, red, gbuf, h1w, h2r, h2w, c2, i, j, tid);
    gbar(bar, ep++, j, sg, false);
    fc2_phase(h2w, wsTf, yb, lds_bc, condY_l, red, i, j, tid);
    gbar(bar, ep++, j, sg, false);
    // ---- phase D (group-local): fc3, argmax, next x for row drow ----
    if (dOwner) {
      if (tid < 512) lds_y[tid] = gld(yb + (size_t)tid*BB + drow);
      __syncthreads();
      int o = 0, kc = 0;
      bool active = false;
      if (tid < 512)      { o = tid & 31; kc = tid >> 5; active = true; }
      else if (tid < 528) { o = 32;       kc = tid - 512; active = true; }
      if (active) {
        float p = 0.f;
        const float* fw = fc3W + (size_t)o*HH + kc*32;
        #pragma unroll
        for (int k2 = 0; k2 < 32; ++k2) p += fw[k2] * lds_y[kc*32 + k2];
        part[o][kc] = p;
      }
      __syncthreads();
      float predv = -1e30f;
      if (tid < NOUT) {
        float s = fc3b[tid];
        #pragma unroll
        for (int kc2 = 0; kc2 < 16; ++kc2) s += part[tid][kc2];
        predv = s;
        out[(size_t)(drow*TT + t)*NOUT + tid] = s;
      }
      if (tid < 64) {
        float v  = (tid < 32) ? predv : -1e30f;
        int  idx = tid;
        #pragma unroll
        for (int off = 32; off > 0; off >>= 1) {
          float ov = __shfl_xor(v, off);
          int   oi = __shfl_xor(idx, off);
          if (ov > v || (ov == v && oi < idx)) { v = ov; idx = oi; }
        }
        if (tid == 0) lds_act = idx;
      }
      __syncthreads();
      const int act = lds_act;
      if (tid < 512)
        gst(xbuf + (size_t)tid*BB + drow, (tid < HH-1) ? emb[(size_t)act*(HH-1) + tid] : 1.0f);
    }
    gbar(bar, ep++, j, sg, false);
  }

  // ---- postprocess row drow ----
  if (dOwner && tid < TT) {
    const int s = tid;
    float* po = out + (size_t)(drow*TT + s)*NOUT;
    float v[NOUT];
    #pragma unroll
    for (int o = 0; o < NOUT; ++o) v[o] = po[o];
    float m = v[0];
    #pragma unroll
    for (int o = 1; o < 32; ++o) m = fmaxf(m, v[o]);
    float sum = 0.f;
    #pragma unroll
    for (int o = 0; o < 32; ++o) sum += expf(v[o] - m);
    float lse = m + logf(sum);
    #pragma unroll
    for (int o = 0; o < 32; ++o) po[o] = v[o] - lse;
    float d = v[32];
    float dm = d;
    #pragma unroll
    for (int off = 32; off > 0; off >>= 1) dm = fmaxf(dm, __shfl_xor(dm, off));
    float e = expf(d - dm);
    float es = e;
    #pragma unroll
    for (int off = 32; off > 0; off >>= 1) es += __shfl_xor(es, off);
    po[32] = e / es;
  }
}

extern "C" void kernel_launch(void* const* d_in, const int* in_sizes, int n_in,
                              void* d_out, int out_size, void* d_ws, size_t ws_size,
                              hipStream_t stream) {
  const float* h0   = (const float*)d_in[1];
  const float* c0   = (const float*)d_in[2];
  const float* cnd  = (const float*)d_in[3];
  const float* emb  = (const float*)d_in[4];
  const float* Wih  = (const float*)d_in[5];
  const float* Whh  = (const float*)d_in[6];
  const float* bih  = (const float*)d_in[7];
  const float* bhh  = (const float*)d_in[8];
  const float* fcW  = (const float*)d_in[9];
  const float* fcb  = (const float*)d_in[10];
  const float* fc2W = (const float*)d_in[11];
  const float* fc2b = (const float*)d_in[12];
  const float* fc3W = (const float*)d_in[13];
  const float* fc3b = (const float*)d_in[14];

  unsigned* bar = (unsigned*)d_ws;
  float* wsf = (float*)((char*)d_ws + 4096);
  float* wsT = wsf + 7*SZ;

  (void)hipMemsetAsync(d_ws, 0, 4096, stream);

  hipLaunchKernelGGL(transpose_weights, dim3(128), dim3(256), 0, stream,
                     Wih, Whh, fc2W, wsT);
  hipLaunchKernelGGL(decoder_kernel, dim3(NWG), dim3(NTHR), 0, stream,
                     h0, c0, cnd, emb, wsT, bih, bhh, fcW, fcb,
                     fc2W, fc2b, fc3W, fc3b, (float*)d_out, bar, wsf);
}